// Round 7
// baseline (946.359 us; speedup 1.0000x reference)
//
#include <hip/hip_runtime.h>

#define HID 128
#define LDP 136   // padded LDS row stride in bf16 elems (272 B)

typedef short s16x8 __attribute__((ext_vector_type(8)));
typedef float f32x4 __attribute__((ext_vector_type(4)));

__device__ __forceinline__ float bf2f(unsigned int u) {
  union { unsigned int i; float f; } v; v.i = u << 16; return v.f;
}
__device__ __forceinline__ float asf(unsigned int u) {
  union { unsigned int i; float f; } v; v.i = u; return v.f;
}
__device__ __forceinline__ unsigned short f2bf(float f) {
  union { float f; unsigned int i; } v; v.f = f;
  unsigned int r = v.i + 0x7fffu + ((v.i >> 16) & 1u);
  return (unsigned short)(r >> 16);
}

// ---------------- zero fill ----------------
__global__ void k_zero(float* __restrict__ p, size_t n) {
  size_t i = (size_t)blockIdx.x * blockDim.x + threadIdx.x;
  if (i < n) p[i] = 0.f;
}

// ---------------- counting sort ----------------
__global__ void k_hist(const int* __restrict__ dst, int* __restrict__ deg, int nE) {
  int e = blockIdx.x * blockDim.x + threadIdx.x;
  if (e < nE) atomicAdd(&deg[dst[e]], 1);
}

__global__ void k_scanA(const int* __restrict__ deg, int* __restrict__ bsum) {
  __shared__ int ss[256];
  int t = threadIdx.x;
  ss[t] = deg[blockIdx.x * 256 + t];
  __syncthreads();
  for (int off = 128; off; off >>= 1) {
    if (t < off) ss[t] += ss[t + off];
    __syncthreads();
  }
  if (t == 0) bsum[blockIdx.x] = ss[0];
}

__global__ void k_scanB(const int* __restrict__ bsum, int* __restrict__ bsumx, int NB) {
  __shared__ int sd[512];
  int t = threadIdx.x;
  int v = (t < NB) ? bsum[t] : 0;
  sd[t] = v;
  __syncthreads();
  for (int off = 1; off < 512; off <<= 1) {
    int a = (t >= off) ? sd[t - off] : 0;
    __syncthreads();
    sd[t] += a;
    __syncthreads();
  }
  if (t < NB) bsumx[t] = sd[t] - v;
}

__global__ void k_scanC(const int* __restrict__ deg, const int* __restrict__ bsumx,
                        int* __restrict__ cursor) {
  __shared__ int ss[256];
  int t = threadIdx.x, i = blockIdx.x * 256 + t;
  int v = deg[i];
  ss[t] = v;
  __syncthreads();
  for (int off = 1; off < 256; off <<= 1) {
    int a = (t >= off) ? ss[t - off] : 0;
    __syncthreads();
    ss[t] += a;
    __syncthreads();
  }
  cursor[i] = ss[t] - v + bsumx[blockIdx.x];
}

__global__ void k_scatter(const int* __restrict__ src, const int* __restrict__ dst,
                          const float* __restrict__ ea, int* __restrict__ cursor,
                          int* __restrict__ src_s, int* __restrict__ dst_s,
                          float* __restrict__ ea_s, int nE) {
  int e = blockIdx.x * blockDim.x + threadIdx.x;
  if (e >= nE) return;
  int d = dst[e];
  int pos = atomicAdd(&cursor[d], 1);
  src_s[pos] = src[e];
  dst_s[pos] = d;
  ea_s[(size_t)pos * 3 + 0] = ea[(size_t)e * 3 + 0];
  ea_s[(size_t)pos * 3 + 1] = ea[(size_t)e * 3 + 1];
  ea_s[(size_t)pos * 3 + 2] = ea[(size_t)e * 3 + 2];
}

// ---------------- transpose weights to bf16 ----------------
__global__ void k_prep_w(const float* __restrict__ ew2, const float* __restrict__ cw1,
                         const float* __restrict__ cw2, unsigned short* __restrict__ wT) {
  int idx = blockIdx.x * blockDim.x + threadIdx.x;
  if (idx >= 7 * 16384) return;
  int m = idx >> 14, i = idx & 16383;
  int n = i >> 7, k = i & 127;
  const float* s = (m == 0) ? ew2 : (m <= 3 ? cw1 + (size_t)(m - 1) * 16384
                                            : cw2 + (size_t)(m - 4) * 16384);
  wT[idx] = f2bf(s[k * 128 + n]);
}

// ---------------- node encoder ----------------
__global__ void k_node_enc(const float* __restrict__ x, const float* __restrict__ w,
                           const float* __restrict__ b, unsigned short* __restrict__ h16, int nN) {
  int idx = blockIdx.x * blockDim.x + threadIdx.x;
  if (idx >= nN * HID) return;
  int i = idx >> 7, j = idx & 127;
  float acc = b[j];
  const float* xr = x + (size_t)i * 7;
#pragma unroll
  for (int k = 0; k < 7; ++k) acc += xr[k] * w[k * HID + j];
  h16[idx] = f2bf(acc);
}

// ---------------- fused per-layer: edge GEMM (recompute) + message + scatter ----------------
// stage1+MFMA produce e in LDS; phase P: m = relu(h[src]+e) vectorized;
// phase W: contiguous-flush segment walk (round-6 verified geometry).
__global__ void __launch_bounds__(256) k_msg5(
    const float* __restrict__ ea_s, const float* __restrict__ ew1, const float* __restrict__ eb1,
    const unsigned short* __restrict__ w2t, const float* __restrict__ eb2,
    const unsigned short* __restrict__ h16,
    const int* __restrict__ src_s, const int* __restrict__ dst_s,
    float* __restrict__ agg, int nE) {
  __shared__ __attribute__((aligned(16))) unsigned short ms[128 * LDP];
  __shared__ float eaL[384];
  __shared__ int srcL[128];
  __shared__ int dstL[128];
  int tid = threadIdx.x;
  int e0 = blockIdx.x * 128;                      // nE % 128 == 0
  for (int i = tid; i < 384; i += 256) eaL[i] = ea_s[(size_t)e0 * 3 + i];
  if (tid < 128) { srcL[tid] = src_s[e0 + tid]; dstL[tid] = dst_s[e0 + tid]; }
  __syncthreads();
  // stage 1: T = relu(ea@w1+b1) bf16 -> ms
  {
    int j = tid & 127, r0 = (tid >> 7) * 64;
    float wa = ew1[j], wb = ew1[HID + j], wc = ew1[2 * HID + j], bj = eb1[j];
    for (int r = r0; r < r0 + 64; ++r) {
      float a = bj + eaL[r * 3] * wa + eaL[r * 3 + 1] * wb + eaL[r * 3 + 2] * wc;
      ms[r * LDP + j] = f2bf(fmaxf(a, 0.f));
    }
  }
  __syncthreads();
  // MFMA: e = T @ W2   (per wave: 64 rows x 64 cols)
  int wave = tid >> 6, lane = tid & 63;
  int l15 = lane & 15, quad = lane >> 4;
  int rbase = (wave >> 1) * 64, nbase = (wave & 1) * 64;
  f32x4 acc[4][4];
#pragma unroll
  for (int i = 0; i < 4; ++i)
#pragma unroll
    for (int j = 0; j < 4; ++j) acc[i][j] = (f32x4){0.f, 0.f, 0.f, 0.f};
  for (int kc = 0; kc < 4; ++kc) {
    int k0 = kc * 32 + quad * 8;
    s16x8 af[4], bf[4];
#pragma unroll
    for (int t = 0; t < 4; ++t)
      af[t] = *(const s16x8*)&ms[(rbase + t * 16 + l15) * LDP + k0];
#pragma unroll
    for (int t = 0; t < 4; ++t)
      bf[t] = *(const s16x8*)&w2t[(size_t)(nbase + t * 16 + l15) * HID + k0];
#pragma unroll
    for (int i = 0; i < 4; ++i)
#pragma unroll
      for (int j = 0; j < 4; ++j)
        acc[i][j] = __builtin_amdgcn_mfma_f32_16x16x32_bf16(af[i], bf[j], acc[i][j], 0, 0, 0);
  }
  __syncthreads();   // all T reads done before e overwrites ms
  // scatter e = acc + eb2 into ms (bf16, C/D layout: col=lane&15, row=quad*4+reg)
  {
    float ebv[4];
#pragma unroll
    for (int t = 0; t < 4; ++t) ebv[t] = eb2[nbase + t * 16 + l15];
#pragma unroll
    for (int tr = 0; tr < 4; ++tr)
#pragma unroll
      for (int reg = 0; reg < 4; ++reg) {
        int row = rbase + tr * 16 + quad * 4 + reg;
#pragma unroll
        for (int tc = 0; tc < 4; ++tc) {
          int col = nbase + tc * 16 + l15;
          ms[row * LDP + col] = f2bf(acc[tr][tc][reg] + ebv[tc]);
        }
      }
  }
  __syncthreads();
  // phase P: m = relu(h16[src] + e), 16B-vectorized gather, in-place in ms
  {
    int r = tid >> 1, cb = (tid & 1) * 64;
    const uint4* hp = (const uint4*)(h16 + (size_t)srcL[r] * HID + cb);
    uint4 hv[8], ev[8];
#pragma unroll
    for (int j = 0; j < 8; ++j) hv[j] = hp[j];
#pragma unroll
    for (int j = 0; j < 8; ++j) ev[j] = *(const uint4*)&ms[r * LDP + cb + j * 8];
#pragma unroll
    for (int j = 0; j < 8; ++j) {
      const unsigned int* hh = (const unsigned int*)&hv[j];
      const unsigned int* ee = (const unsigned int*)&ev[j];
      uint4 o;
      unsigned int* oo = (unsigned int*)&o;
#pragma unroll
      for (int q = 0; q < 4; ++q) {
        float a0 = asf(hh[q] << 16), a1 = asf(hh[q] & 0xffff0000u);
        float b0 = asf(ee[q] << 16), b1 = asf(ee[q] & 0xffff0000u);
        float m0 = fmaxf(a0 + b0, 0.f), m1 = fmaxf(a1 + b1, 0.f);
        oo[q] = (unsigned int)f2bf(m0) | ((unsigned int)f2bf(m1) << 16);
      }
      *(uint4*)&ms[r * LDP + cb + j * 8] = o;
    }
  }
  __syncthreads();
  // phase W: wave = 64 contiguous cols, uniform row walk, coalesced flushes
  {
    int half = tid >> 7, col = tid & 127;
    int rs = half * 64;
    int cur = -1;
    float s = 0.f;
    for (int r = rs; r < rs + 64; ++r) {
      int d = dstL[r];                              // wave-uniform broadcast
      float v = bf2f((unsigned int)ms[r * LDP + col]);
      if (d != cur) {
        if (cur >= 0) atomicAdd(&agg[(size_t)cur * HID + col], s);
        cur = d; s = v;
      } else s += v;
    }
    atomicAdd(&agg[(size_t)cur * HID + col], s);
  }
}

// ---------------- conv MLP ----------------
__global__ void __launch_bounds__(256) k_conv_mfma(
    const unsigned short* __restrict__ h16in, const float* __restrict__ agg,
    const unsigned short* __restrict__ w1t, const float* __restrict__ b1,
    const unsigned short* __restrict__ w2t, const float* __restrict__ b2,
    unsigned short* __restrict__ h16out, int nN) {
  __shared__ __attribute__((aligned(16))) unsigned short zs[128 * LDP];
  int tid = threadIdx.x;
  int n0 = blockIdx.x * 128;
  for (int it = 0; it < 16; ++it) {
    int elem = (it * 256 + tid) * 4;
    int r = elem >> 7, c = elem & 127;
    int grow = n0 + r;
    uint2 zp = {0u, 0u};
    if (grow < nN) {
      uint2 hu = *(const uint2*)(h16in + (size_t)grow * HID + c);
      float4 a4 = *(const float4*)(agg + (size_t)grow * HID + c);
      unsigned short z0 = f2bf(bf2f(hu.x & 0xffffu) + a4.x);
      unsigned short z1 = f2bf(bf2f(hu.x >> 16) + a4.y);
      unsigned short z2 = f2bf(bf2f(hu.y & 0xffffu) + a4.z);
      unsigned short z3 = f2bf(bf2f(hu.y >> 16) + a4.w);
      zp.x = (unsigned int)z0 | ((unsigned int)z1 << 16);
      zp.y = (unsigned int)z2 | ((unsigned int)z3 << 16);
    }
    *(uint2*)&zs[r * LDP + c] = zp;
  }
  __syncthreads();
  int wave = tid >> 6, lane = tid & 63;
  int l15 = lane & 15, quad = lane >> 4;
  int rbase = (wave >> 1) * 64, nbase = (wave & 1) * 64;
  f32x4 acc[4][4];
#pragma unroll
  for (int i = 0; i < 4; ++i)
#pragma unroll
    for (int j = 0; j < 4; ++j) acc[i][j] = (f32x4){0.f, 0.f, 0.f, 0.f};
  for (int kc = 0; kc < 4; ++kc) {
    int k0 = kc * 32 + quad * 8;
    s16x8 af[4], bf[4];
#pragma unroll
    for (int t = 0; t < 4; ++t)
      af[t] = *(const s16x8*)&zs[(rbase + t * 16 + l15) * LDP + k0];
#pragma unroll
    for (int t = 0; t < 4; ++t)
      bf[t] = *(const s16x8*)&w1t[(size_t)(nbase + t * 16 + l15) * HID + k0];
#pragma unroll
    for (int i = 0; i < 4; ++i)
#pragma unroll
      for (int j = 0; j < 4; ++j)
        acc[i][j] = __builtin_amdgcn_mfma_f32_16x16x32_bf16(af[i], bf[j], acc[i][j], 0, 0, 0);
  }
  __syncthreads();
  {
    float bv[4];
#pragma unroll
    for (int t = 0; t < 4; ++t) bv[t] = b1[nbase + t * 16 + l15];
#pragma unroll
    for (int tr = 0; tr < 4; ++tr)
#pragma unroll
      for (int tc = 0; tc < 4; ++tc)
#pragma unroll
        for (int reg = 0; reg < 4; ++reg) {
          int row = rbase + tr * 16 + quad * 4 + reg;
          int col = nbase + tc * 16 + l15;
          zs[row * LDP + col] = f2bf(fmaxf(acc[tr][tc][reg] + bv[tc], 0.f));
        }
  }
  __syncthreads();
#pragma unroll
  for (int i = 0; i < 4; ++i)
#pragma unroll
    for (int j = 0; j < 4; ++j) acc[i][j] = (f32x4){0.f, 0.f, 0.f, 0.f};
  for (int kc = 0; kc < 4; ++kc) {
    int k0 = kc * 32 + quad * 8;
    s16x8 af[4], bf[4];
#pragma unroll
    for (int t = 0; t < 4; ++t)
      af[t] = *(const s16x8*)&zs[(rbase + t * 16 + l15) * LDP + k0];
#pragma unroll
    for (int t = 0; t < 4; ++t)
      bf[t] = *(const s16x8*)&w2t[(size_t)(nbase + t * 16 + l15) * HID + k0];
#pragma unroll
    for (int i = 0; i < 4; ++i)
#pragma unroll
      for (int j = 0; j < 4; ++j)
        acc[i][j] = __builtin_amdgcn_mfma_f32_16x16x32_bf16(af[i], bf[j], acc[i][j], 0, 0, 0);
  }
  {
    float bv[4];
#pragma unroll
    for (int t = 0; t < 4; ++t) bv[t] = b2[nbase + t * 16 + l15];
#pragma unroll
    for (int tr = 0; tr < 4; ++tr)
#pragma unroll
      for (int reg = 0; reg < 4; ++reg) {
        int grow = n0 + rbase + tr * 16 + quad * 4 + reg;
        if (grow < nN) {
#pragma unroll
          for (int tc = 0; tc < 4; ++tc) {
            int col = nbase + tc * 16 + l15;
            h16out[(size_t)grow * HID + col] = f2bf(fmaxf(acc[tr][tc][reg] + bv[tc], 0.f));
          }
        }
      }
  }
}

// ---------------- counts ----------------
__global__ void k_counts(const int* __restrict__ batch, int* __restrict__ cnts, int nN) {
  int i = blockIdx.x * blockDim.x + threadIdx.x;
  if (i < nN) atomicAdd(&cnts[batch[i]], 1);
}

// ---------------- segment-reduced pool (batch sorted) ----------------
__global__ void __launch_bounds__(256) k_pool2(
    const unsigned short* __restrict__ h16, const int* __restrict__ batch,
    float* __restrict__ g, int nN) {
  __shared__ int bL[128];
  int tid = threadIdx.x;
  int n0 = blockIdx.x * 128;
  if (tid < 128) {
    int n = n0 + tid;
    bL[tid] = (n < nN) ? batch[n] : -1;
  }
  __syncthreads();
  int half = tid >> 7, col = tid & 127;
  int rs = half * 64;
  int cur = -1;
  float s = 0.f;
  for (int r = rs; r < rs + 64; ++r) {
    int b = bL[r];
    float v = (b >= 0) ? bf2f((unsigned int)h16[(size_t)(n0 + r) * HID + col]) : 0.f;
    if (b != cur) {
      if (cur >= 0) atomicAdd(&g[(size_t)cur * HID + col], s);
      cur = b; s = v;
    } else s += v;
  }
  if (cur >= 0) atomicAdd(&g[(size_t)cur * HID + col], s);
}

// ---------------- heads ----------------
__global__ void __launch_bounds__(128) k_head(
    const float* __restrict__ g, const int* __restrict__ counts,
    const float* __restrict__ clw1, const float* __restrict__ clb1,
    const float* __restrict__ clw2, const float* __restrict__ clb2,
    const float* __restrict__ rw1, const float* __restrict__ rb1,
    const float* __restrict__ rw2, const float* __restrict__ rb2,
    float* __restrict__ out, int nG) {
  __shared__ float gs[HID];
  int b = blockIdx.x;
  int tid = threadIdx.x;
  float cnt = fmaxf((float)counts[b], 1.f);
  gs[tid] = g[b * HID + tid] / cnt;
  __syncthreads();
  int wave = tid >> 6, lane = tid & 63;
  const float* w1 = wave ? rw1 : clw1;
  const float* b1 = wave ? rb1 : clb1;
  const float* w2 = wave ? rw2 : clw2;
  const float* b2 = wave ? rb2 : clb2;
  float acc = b1[lane];
  for (int k = 0; k < HID; ++k) acc += gs[k] * w1[k * 64 + lane];
  acc = fmaxf(acc, 0.f) * w2[lane];
#pragma unroll
  for (int off = 32; off; off >>= 1) acc += __shfl_down(acc, off);
  if (lane == 0) out[wave * nG + b] = acc + b2[0];
}

extern "C" void kernel_launch(void* const* d_in, const int* in_sizes, int n_in,
                              void* d_out, int out_size, void* d_ws, size_t ws_size,
                              hipStream_t stream) {
  const float* x      = (const float*)d_in[0];
  const float* ea     = (const float*)d_in[1];
  const int*   eidx   = (const int*)d_in[2];
  const int*   batch  = (const int*)d_in[3];
  const float* node_w = (const float*)d_in[4];
  const float* node_b = (const float*)d_in[5];
  const float* ew1    = (const float*)d_in[6];
  const float* eb1    = (const float*)d_in[7];
  const float* ew2    = (const float*)d_in[8];
  const float* eb2    = (const float*)d_in[9];
  const float* cw1    = (const float*)d_in[10];
  const float* cb1    = (const float*)d_in[11];
  const float* cw2    = (const float*)d_in[12];
  const float* cb2    = (const float*)d_in[13];
  const float* clw1   = (const float*)d_in[14];
  const float* clb1   = (const float*)d_in[15];
  const float* clw2   = (const float*)d_in[16];
  const float* clb2   = (const float*)d_in[17];
  const float* rw1    = (const float*)d_in[18];
  const float* rb1    = (const float*)d_in[19];
  const float* rw2    = (const float*)d_in[20];
  const float* rb2    = (const float*)d_in[21];
  float* out = (float*)d_out;

  int nN = in_sizes[3];        // 100000
  int nE = in_sizes[2] / 2;    // 640000 (divisible by 128)
  int nG = out_size / 2;       // 2048
  const int* src = eidx;
  const int* dst = eidx + nE;

  int NB = (nN + 255) / 256;
  int bins = NB * 256;

  // ---- workspace (~92 MB) ----
  size_t hN = (size_t)nN * HID;
  size_t gN = (size_t)nG * HID;
  float* agg = (float*)d_ws;                        // hN f32
  float* g   = agg + hN;                            // gN f32
  int*   cnts = (int*)(g + gN);                     // nG
  unsigned short* wT  = (unsigned short*)(cnts + nG);  // 7*16384 bf16
  unsigned short* h16 = wT + 7 * 16384;             // hN bf16
  int* deg    = (int*)(h16 + hN);                   // bins
  int* cursor = deg + bins;                         // bins
  int* bsum   = cursor + bins;                      // 512
  int* bsumx  = bsum + 512;                         // 512
  int* src_s  = bsumx + 512;                        // nE
  int* dst_s  = src_s + nE;                         // nE
  float* ea_s = (float*)(dst_s + nE);               // 3*nE f32

  // ---- counting sort of edges by dst ----
  k_zero<<<(bins + 255) / 256, 256, 0, stream>>>((float*)deg, bins);
  k_hist<<<(nE + 255) / 256, 256, 0, stream>>>(dst, deg, nE);
  k_scanA<<<NB, 256, 0, stream>>>(deg, bsum);
  k_scanB<<<1, 512, 0, stream>>>(bsum, bsumx, NB);
  k_scanC<<<NB, 256, 0, stream>>>(deg, bsumx, cursor);
  k_scatter<<<(nE + 255) / 256, 256, 0, stream>>>(src, dst, ea, cursor,
                                                  src_s, dst_s, ea_s, nE);

  k_prep_w<<<(7 * 16384 + 255) / 256, 256, 0, stream>>>(ew2, cw1, cw2, wT);
  k_node_enc<<<(nN * HID + 255) / 256, 256, 0, stream>>>(x, node_w, node_b, h16, nN);

  int zeroBlocks = (int)((hN + 255) / 256);
  for (int l = 0; l < 3; ++l) {
    k_zero<<<zeroBlocks, 256, 0, stream>>>(agg, hN);
    k_msg5<<<nE / 128, 256, 0, stream>>>(ea_s, ew1, eb1, wT, eb2, h16,
                                         src_s, dst_s, agg, nE);
    k_conv_mfma<<<(nN + 127) / 128, 256, 0, stream>>>(
        h16, agg, wT + (size_t)(1 + l) * 16384, cb1 + (size_t)l * HID,
        wT + (size_t)(4 + l) * 16384, cb2 + (size_t)l * HID, h16, nN);
  }

  k_zero<<<(int)((gN + nG + 255) / 256), 256, 0, stream>>>(g, gN + nG);
  k_counts<<<(nN + 255) / 256, 256, 0, stream>>>(batch, cnts, nN);
  k_pool2<<<(nN + 127) / 128, 256, 0, stream>>>(h16, batch, g, nN);
  k_head<<<nG, 128, 0, stream>>>(g, cnts, clw1, clb1, clw2, clb2,
                                 rw1, rb1, rw2, rb2, out, nG);
}

// Round 8
// 687.225 us; speedup vs baseline: 1.3771x; 1.3771x over previous
//
#include <hip/hip_runtime.h>

#define HID 128
#define LDP 136   // padded LDS row stride in bf16 elems (272 B, 16B-aligned)

typedef short s16x8 __attribute__((ext_vector_type(8)));
typedef float f32x4 __attribute__((ext_vector_type(4)));

__device__ __forceinline__ float bf2f(unsigned int u) {
  union { unsigned int i; float f; } v; v.i = u << 16; return v.f;
}
__device__ __forceinline__ float asf(unsigned int u) {
  union { unsigned int i; float f; } v; v.i = u; return v.f;
}
__device__ __forceinline__ unsigned short f2bf(float f) {
  union { float f; unsigned int i; } v; v.f = f;
  unsigned int r = v.i + 0x7fffu + ((v.i >> 16) & 1u);
  return (unsigned short)(r >> 16);
}

// ---------------- zero fill (vectorized) ----------------
__global__ void k_zero4(float4* __restrict__ p, size_t n4) {
  size_t i = (size_t)blockIdx.x * blockDim.x + threadIdx.x;
  if (i < n4) p[i] = (float4){0.f, 0.f, 0.f, 0.f};
}

// ---------------- counting sort ----------------
__global__ void k_hist(const int* __restrict__ dst, int* __restrict__ deg, int nE) {
  int e = blockIdx.x * blockDim.x + threadIdx.x;
  if (e < nE) atomicAdd(&deg[dst[e]], 1);
}

__global__ void k_scanA(const int* __restrict__ deg, int* __restrict__ bsum) {
  __shared__ int ss[256];
  int t = threadIdx.x;
  ss[t] = deg[blockIdx.x * 256 + t];
  __syncthreads();
  for (int off = 128; off; off >>= 1) {
    if (t < off) ss[t] += ss[t + off];
    __syncthreads();
  }
  if (t == 0) bsum[blockIdx.x] = ss[0];
}

__global__ void k_scanB(const int* __restrict__ bsum, int* __restrict__ bsumx, int NB) {
  __shared__ int sd[512];
  int t = threadIdx.x;
  int v = (t < NB) ? bsum[t] : 0;
  sd[t] = v;
  __syncthreads();
  for (int off = 1; off < 512; off <<= 1) {
    int a = (t >= off) ? sd[t - off] : 0;
    __syncthreads();
    sd[t] += a;
    __syncthreads();
  }
  if (t < NB) bsumx[t] = sd[t] - v;
}

__global__ void k_scanC(const int* __restrict__ deg, const int* __restrict__ bsumx,
                        int* __restrict__ cursor) {
  __shared__ int ss[256];
  int t = threadIdx.x, i = blockIdx.x * 256 + t;
  int v = deg[i];
  ss[t] = v;
  __syncthreads();
  for (int off = 1; off < 256; off <<= 1) {
    int a = (t >= off) ? ss[t - off] : 0;
    __syncthreads();
    ss[t] += a;
    __syncthreads();
  }
  cursor[i] = ss[t] - v + bsumx[blockIdx.x];
}

__global__ void k_scatter(const int* __restrict__ src, const int* __restrict__ dst,
                          const float* __restrict__ ea, int* __restrict__ cursor,
                          int* __restrict__ src_s, int* __restrict__ dst_s,
                          float* __restrict__ ea_s, int nE) {
  int e = blockIdx.x * blockDim.x + threadIdx.x;
  if (e >= nE) return;
  int d = dst[e];
  int pos = atomicAdd(&cursor[d], 1);
  src_s[pos] = src[e];
  dst_s[pos] = d;
  ea_s[(size_t)pos * 3 + 0] = ea[(size_t)e * 3 + 0];
  ea_s[(size_t)pos * 3 + 1] = ea[(size_t)e * 3 + 1];
  ea_s[(size_t)pos * 3 + 2] = ea[(size_t)e * 3 + 2];
}

// ---------------- transpose weights to bf16 ----------------
__global__ void k_prep_w(const float* __restrict__ ew2, const float* __restrict__ cw1,
                         const float* __restrict__ cw2, unsigned short* __restrict__ wT) {
  int idx = blockIdx.x * blockDim.x + threadIdx.x;
  if (idx >= 7 * 16384) return;
  int m = idx >> 14, i = idx & 16383;
  int n = i >> 7, k = i & 127;
  const float* s = (m == 0) ? ew2 : (m <= 3 ? cw1 + (size_t)(m - 1) * 16384
                                            : cw2 + (size_t)(m - 4) * 16384);
  wT[idx] = f2bf(s[k * 128 + n]);
}

// ---------------- node encoder ----------------
__global__ void k_node_enc(const float* __restrict__ x, const float* __restrict__ w,
                           const float* __restrict__ b, unsigned short* __restrict__ h16, int nN) {
  int idx = blockIdx.x * blockDim.x + threadIdx.x;
  if (idx >= nN * HID) return;
  int i = idx >> 7, j = idx & 127;
  float acc = b[j];
  const float* xr = x + (size_t)i * 7;
#pragma unroll
  for (int k = 0; k < 7; ++k) acc += xr[k] * w[k * HID + j];
  h16[idx] = f2bf(acc);
}

// ---------------- one-time edge encoder GEMM -> e16 (sorted order, bf16) ----------------
// epilogue: C/D scatter -> LDS, then coalesced uint4 global stores
__global__ void __launch_bounds__(256) k_edge_gemm(
    const float* __restrict__ ea_s, const float* __restrict__ ew1, const float* __restrict__ eb1,
    const unsigned short* __restrict__ w2t, const float* __restrict__ eb2,
    unsigned short* __restrict__ e16, int nE) {
  __shared__ __attribute__((aligned(16))) unsigned short ms[128 * LDP];
  __shared__ float eaL[384];
  int tid = threadIdx.x;
  int e0 = blockIdx.x * 128;                      // nE % 128 == 0
  for (int i = tid; i < 384; i += 256) eaL[i] = ea_s[(size_t)e0 * 3 + i];
  __syncthreads();
  // stage 1: T = relu(ea@w1+b1) bf16 -> ms
  {
    int j = tid & 127, r0 = (tid >> 7) * 64;
    float wa = ew1[j], wb = ew1[HID + j], wc = ew1[2 * HID + j], bj = eb1[j];
    for (int r = r0; r < r0 + 64; ++r) {
      float a = bj + eaL[r * 3] * wa + eaL[r * 3 + 1] * wb + eaL[r * 3 + 2] * wc;
      ms[r * LDP + j] = f2bf(fmaxf(a, 0.f));
    }
  }
  __syncthreads();
  int wave = tid >> 6, lane = tid & 63;
  int l15 = lane & 15, quad = lane >> 4;
  int rbase = (wave >> 1) * 64, nbase = (wave & 1) * 64;
  f32x4 acc[4][4];
#pragma unroll
  for (int i = 0; i < 4; ++i)
#pragma unroll
    for (int j = 0; j < 4; ++j) acc[i][j] = (f32x4){0.f, 0.f, 0.f, 0.f};
  for (int kc = 0; kc < 4; ++kc) {
    int k0 = kc * 32 + quad * 8;
    s16x8 af[4], bf[4];
#pragma unroll
    for (int t = 0; t < 4; ++t)
      af[t] = *(const s16x8*)&ms[(rbase + t * 16 + l15) * LDP + k0];
#pragma unroll
    for (int t = 0; t < 4; ++t)
      bf[t] = *(const s16x8*)&w2t[(size_t)(nbase + t * 16 + l15) * HID + k0];
#pragma unroll
    for (int i = 0; i < 4; ++i)
#pragma unroll
      for (int j = 0; j < 4; ++j)
        acc[i][j] = __builtin_amdgcn_mfma_f32_16x16x32_bf16(af[i], bf[j], acc[i][j], 0, 0, 0);
  }
  __syncthreads();   // all T reads done before e overwrites ms
  // e = acc + eb2 -> ms (C/D layout: col=lane&15, row=quad*4+reg)
  {
    float ebv[4];
#pragma unroll
    for (int t = 0; t < 4; ++t) ebv[t] = eb2[nbase + t * 16 + l15];
#pragma unroll
    for (int tr = 0; tr < 4; ++tr)
#pragma unroll
      for (int reg = 0; reg < 4; ++reg) {
        int row = rbase + tr * 16 + quad * 4 + reg;
#pragma unroll
        for (int tc = 0; tc < 4; ++tc) {
          int col = nbase + tc * 16 + l15;
          ms[row * LDP + col] = f2bf(acc[tr][tc][reg] + ebv[tc]);
        }
      }
  }
  __syncthreads();
  // coalesced store: 2048 uint4 / 256 threads = 8 each; wave covers 4 full rows (1 KB)
#pragma unroll
  for (int it = 0; it < 8; ++it) {
    int idx = it * 256 + tid;
    int r = idx >> 4, c8 = (idx & 15) * 8;
    *(uint4*)&e16[(size_t)(e0 + r) * HID + c8] = *(const uint4*)&ms[r * LDP + c8];
  }
}

// ---------------- per-layer message + segment-reduced scatter (512 threads) ----------------
// phase P: m = relu(h16[src]+e16) vectorized into LDS
// phase W: 4 row-quarters x 128 cols; wave = 64 contiguous cols, uniform walk,
//          contiguous 256B atomic flushes (round-6 verified geometry, half the walk)
__global__ void __launch_bounds__(512) k_msg6(
    const unsigned short* __restrict__ e16, const unsigned short* __restrict__ h16,
    const int* __restrict__ src_s, const int* __restrict__ dst_s,
    float* __restrict__ agg, int nE) {
  __shared__ __attribute__((aligned(16))) unsigned short ms[128 * LDP];
  __shared__ int srcL[128];
  __shared__ int dstL[128];
  int tid = threadIdx.x;
  int e0 = blockIdx.x * 128;                      // nE % 128 == 0
  if (tid < 128) { srcL[tid] = src_s[e0 + tid]; dstL[tid] = dst_s[e0 + tid]; }
  __syncthreads();
  // phase P: thread = (row, 32-col chunk); 4 uint4 loads each of h and e
  {
    int r = tid >> 2, cb = (tid & 3) * 32;
    const uint4* hp = (const uint4*)(h16 + (size_t)srcL[r] * HID + cb);
    const uint4* ep = (const uint4*)(e16 + (size_t)(e0 + r) * HID + cb);
    uint4 hv[4], ev[4];
#pragma unroll
    for (int j = 0; j < 4; ++j) hv[j] = hp[j];
#pragma unroll
    for (int j = 0; j < 4; ++j) ev[j] = ep[j];
#pragma unroll
    for (int j = 0; j < 4; ++j) {
      const unsigned int* hh = (const unsigned int*)&hv[j];
      const unsigned int* ee = (const unsigned int*)&ev[j];
      uint4 o;
      unsigned int* oo = (unsigned int*)&o;
#pragma unroll
      for (int q = 0; q < 4; ++q) {
        float a0 = asf(hh[q] << 16), a1 = asf(hh[q] & 0xffff0000u);
        float b0 = asf(ee[q] << 16), b1 = asf(ee[q] & 0xffff0000u);
        float m0 = fmaxf(a0 + b0, 0.f), m1 = fmaxf(a1 + b1, 0.f);
        oo[q] = (unsigned int)f2bf(m0) | ((unsigned int)f2bf(m1) << 16);
      }
      *(uint4*)&ms[r * LDP + cb + j * 8] = o;
    }
  }
  __syncthreads();
  // phase W: quarter = tid>>7 (32 rows), col = tid&127
  {
    int quarter = tid >> 7, col = tid & 127;
    int rs = quarter * 32;
    int cur = -1;
    float s = 0.f;
    for (int r = rs; r < rs + 32; ++r) {
      int d = dstL[r];                              // wave-uniform broadcast
      float v = bf2f((unsigned int)ms[r * LDP + col]);
      if (d != cur) {
        if (cur >= 0) atomicAdd(&agg[(size_t)cur * HID + col], s);
        cur = d; s = v;
      } else s += v;
    }
    atomicAdd(&agg[(size_t)cur * HID + col], s);
  }
}

// ---------------- conv MLP ----------------
__global__ void __launch_bounds__(256) k_conv_mfma(
    const unsigned short* __restrict__ h16in, const float* __restrict__ agg,
    const unsigned short* __restrict__ w1t, const float* __restrict__ b1,
    const unsigned short* __restrict__ w2t, const float* __restrict__ b2,
    unsigned short* __restrict__ h16out, int nN) {
  __shared__ __attribute__((aligned(16))) unsigned short zs[128 * LDP];
  int tid = threadIdx.x;
  int n0 = blockIdx.x * 128;
  for (int it = 0; it < 16; ++it) {
    int elem = (it * 256 + tid) * 4;
    int r = elem >> 7, c = elem & 127;
    int grow = n0 + r;
    uint2 zp = {0u, 0u};
    if (grow < nN) {
      uint2 hu = *(const uint2*)(h16in + (size_t)grow * HID + c);
      float4 a4 = *(const float4*)(agg + (size_t)grow * HID + c);
      unsigned short z0 = f2bf(bf2f(hu.x & 0xffffu) + a4.x);
      unsigned short z1 = f2bf(bf2f(hu.x >> 16) + a4.y);
      unsigned short z2 = f2bf(bf2f(hu.y & 0xffffu) + a4.z);
      unsigned short z3 = f2bf(bf2f(hu.y >> 16) + a4.w);
      zp.x = (unsigned int)z0 | ((unsigned int)z1 << 16);
      zp.y = (unsigned int)z2 | ((unsigned int)z3 << 16);
    }
    *(uint2*)&zs[r * LDP + c] = zp;
  }
  __syncthreads();
  int wave = tid >> 6, lane = tid & 63;
  int l15 = lane & 15, quad = lane >> 4;
  int rbase = (wave >> 1) * 64, nbase = (wave & 1) * 64;
  f32x4 acc[4][4];
#pragma unroll
  for (int i = 0; i < 4; ++i)
#pragma unroll
    for (int j = 0; j < 4; ++j) acc[i][j] = (f32x4){0.f, 0.f, 0.f, 0.f};
  for (int kc = 0; kc < 4; ++kc) {
    int k0 = kc * 32 + quad * 8;
    s16x8 af[4], bf[4];
#pragma unroll
    for (int t = 0; t < 4; ++t)
      af[t] = *(const s16x8*)&zs[(rbase + t * 16 + l15) * LDP + k0];
#pragma unroll
    for (int t = 0; t < 4; ++t)
      bf[t] = *(const s16x8*)&w1t[(size_t)(nbase + t * 16 + l15) * HID + k0];
#pragma unroll
    for (int i = 0; i < 4; ++i)
#pragma unroll
      for (int j = 0; j < 4; ++j)
        acc[i][j] = __builtin_amdgcn_mfma_f32_16x16x32_bf16(af[i], bf[j], acc[i][j], 0, 0, 0);
  }
  __syncthreads();
  {
    float bv[4];
#pragma unroll
    for (int t = 0; t < 4; ++t) bv[t] = b1[nbase + t * 16 + l15];
#pragma unroll
    for (int tr = 0; tr < 4; ++tr)
#pragma unroll
      for (int tc = 0; tc < 4; ++tc)
#pragma unroll
        for (int reg = 0; reg < 4; ++reg) {
          int row = rbase + tr * 16 + quad * 4 + reg;
          int col = nbase + tc * 16 + l15;
          zs[row * LDP + col] = f2bf(fmaxf(acc[tr][tc][reg] + bv[tc], 0.f));
        }
  }
  __syncthreads();
#pragma unroll
  for (int i = 0; i < 4; ++i)
#pragma unroll
    for (int j = 0; j < 4; ++j) acc[i][j] = (f32x4){0.f, 0.f, 0.f, 0.f};
  for (int kc = 0; kc < 4; ++kc) {
    int k0 = kc * 32 + quad * 8;
    s16x8 af[4], bf[4];
#pragma unroll
    for (int t = 0; t < 4; ++t)
      af[t] = *(const s16x8*)&zs[(rbase + t * 16 + l15) * LDP + k0];
#pragma unroll
    for (int t = 0; t < 4; ++t)
      bf[t] = *(const s16x8*)&w2t[(size_t)(nbase + t * 16 + l15) * HID + k0];
#pragma unroll
    for (int i = 0; i < 4; ++i)
#pragma unroll
      for (int j = 0; j < 4; ++j)
        acc[i][j] = __builtin_amdgcn_mfma_f32_16x16x32_bf16(af[i], bf[j], acc[i][j], 0, 0, 0);
  }
  {
    float bv[4];
#pragma unroll
    for (int t = 0; t < 4; ++t) bv[t] = b2[nbase + t * 16 + l15];
#pragma unroll
    for (int tr = 0; tr < 4; ++tr)
#pragma unroll
      for (int reg = 0; reg < 4; ++reg) {
        int grow = n0 + rbase + tr * 16 + quad * 4 + reg;
        if (grow < nN) {
#pragma unroll
          for (int tc = 0; tc < 4; ++tc) {
            int col = nbase + tc * 16 + l15;
            h16out[(size_t)grow * HID + col] = f2bf(fmaxf(acc[tr][tc][reg] + bv[tc], 0.f));
          }
        }
      }
  }
}

// ---------------- counts ----------------
__global__ void k_counts(const int* __restrict__ batch, int* __restrict__ cnts, int nN) {
  int i = blockIdx.x * blockDim.x + threadIdx.x;
  if (i < nN) atomicAdd(&cnts[batch[i]], 1);
}

// ---------------- segment-reduced pool (batch sorted) ----------------
__global__ void __launch_bounds__(256) k_pool2(
    const unsigned short* __restrict__ h16, const int* __restrict__ batch,
    float* __restrict__ g, int nN) {
  __shared__ int bL[128];
  int tid = threadIdx.x;
  int n0 = blockIdx.x * 128;
  if (tid < 128) {
    int n = n0 + tid;
    bL[tid] = (n < nN) ? batch[n] : -1;
  }
  __syncthreads();
  int half = tid >> 7, col = tid & 127;
  int rs = half * 64;
  int cur = -1;
  float s = 0.f;
  for (int r = rs; r < rs + 64; ++r) {
    int b = bL[r];
    float v = (b >= 0) ? bf2f((unsigned int)h16[(size_t)(n0 + r) * HID + col]) : 0.f;
    if (b != cur) {
      if (cur >= 0) atomicAdd(&g[(size_t)cur * HID + col], s);
      cur = b; s = v;
    } else s += v;
  }
  if (cur >= 0) atomicAdd(&g[(size_t)cur * HID + col], s);
}

// ---------------- heads ----------------
__global__ void __launch_bounds__(128) k_head(
    const float* __restrict__ g, const int* __restrict__ counts,
    const float* __restrict__ clw1, const float* __restrict__ clb1,
    const float* __restrict__ clw2, const float* __restrict__ clb2,
    const float* __restrict__ rw1, const float* __restrict__ rb1,
    const float* __restrict__ rw2, const float* __restrict__ rb2,
    float* __restrict__ out, int nG) {
  __shared__ float gs[HID];
  int b = blockIdx.x;
  int tid = threadIdx.x;
  float cnt = fmaxf((float)counts[b], 1.f);
  gs[tid] = g[b * HID + tid] / cnt;
  __syncthreads();
  int wave = tid >> 6, lane = tid & 63;
  const float* w1 = wave ? rw1 : clw1;
  const float* b1 = wave ? rb1 : clb1;
  const float* w2 = wave ? rw2 : clw2;
  const float* b2 = wave ? rb2 : clb2;
  float acc = b1[lane];
  for (int k = 0; k < HID; ++k) acc += gs[k] * w1[k * 64 + lane];
  acc = fmaxf(acc, 0.f) * w2[lane];
#pragma unroll
  for (int off = 32; off; off >>= 1) acc += __shfl_down(acc, off);
  if (lane == 0) out[wave * nG + b] = acc + b2[0];
}

extern "C" void kernel_launch(void* const* d_in, const int* in_sizes, int n_in,
                              void* d_out, int out_size, void* d_ws, size_t ws_size,
                              hipStream_t stream) {
  const float* x      = (const float*)d_in[0];
  const float* ea     = (const float*)d_in[1];
  const int*   eidx   = (const int*)d_in[2];
  const int*   batch  = (const int*)d_in[3];
  const float* node_w = (const float*)d_in[4];
  const float* node_b = (const float*)d_in[5];
  const float* ew1    = (const float*)d_in[6];
  const float* eb1    = (const float*)d_in[7];
  const float* ew2    = (const float*)d_in[8];
  const float* eb2    = (const float*)d_in[9];
  const float* cw1    = (const float*)d_in[10];
  const float* cb1    = (const float*)d_in[11];
  const float* cw2    = (const float*)d_in[12];
  const float* cb2    = (const float*)d_in[13];
  const float* clw1   = (const float*)d_in[14];
  const float* clb1   = (const float*)d_in[15];
  const float* clw2   = (const float*)d_in[16];
  const float* clb2   = (const float*)d_in[17];
  const float* rw1    = (const float*)d_in[18];
  const float* rb1    = (const float*)d_in[19];
  const float* rw2    = (const float*)d_in[20];
  const float* rb2    = (const float*)d_in[21];
  float* out = (float*)d_out;

  int nN = in_sizes[3];        // 100000
  int nE = in_sizes[2] / 2;    // 640000 (divisible by 128)
  int nG = out_size / 2;       // 2048
  const int* src = eidx;
  const int* dst = eidx + nE;

  int NB = (nN + 255) / 256;
  int bins = NB * 256;

  // ---- workspace (~255.5 MB) ----
  size_t hN = (size_t)nN * HID;
  size_t gN = (size_t)nG * HID;
  float* agg = (float*)d_ws;                        // hN f32
  float* g   = agg + hN;                            // gN f32
  int*   cnts = (int*)(g + gN);                     // nG
  unsigned short* wT  = (unsigned short*)(cnts + nG);  // 7*16384 bf16
  unsigned short* h16 = wT + 7 * 16384;             // hN bf16
  int* deg    = (int*)(h16 + hN);                   // bins
  int* cursor = deg + bins;                         // bins
  int* bsum   = cursor + bins;                      // 512
  int* bsumx  = bsum + 512;                         // 512
  int* src_s  = bsumx + 512;                        // nE
  int* dst_s  = src_s + nE;                         // nE
  float* ea_s = (float*)(dst_s + nE);               // 3*nE f32
  unsigned short* e16 = (unsigned short*)(ea_s + (size_t)3 * nE);  // nE*128 bf16

  // ---- counting sort of edges by dst ----
  k_zero4<<<(int)((bins / 4 + 255) / 256), 256, 0, stream>>>((float4*)deg, bins / 4);
  k_hist<<<(nE + 255) / 256, 256, 0, stream>>>(dst, deg, nE);
  k_scanA<<<NB, 256, 0, stream>>>(deg, bsum);
  k_scanB<<<1, 512, 0, stream>>>(bsum, bsumx, NB);
  k_scanC<<<NB, 256, 0, stream>>>(deg, bsumx, cursor);
  k_scatter<<<(nE + 255) / 256, 256, 0, stream>>>(src, dst, ea, cursor,
                                                  src_s, dst_s, ea_s, nE);

  k_prep_w<<<(7 * 16384 + 255) / 256, 256, 0, stream>>>(ew2, cw1, cw2, wT);
  k_edge_gemm<<<nE / 128, 256, 0, stream>>>(ea_s, ew1, eb1, wT, eb2, e16, nE);
  k_node_enc<<<(nN * HID + 255) / 256, 256, 0, stream>>>(x, node_w, node_b, h16, nN);

  int zeroBlocks = (int)((hN / 4 + 255) / 256);
  for (int l = 0; l < 3; ++l) {
    k_zero4<<<zeroBlocks, 256, 0, stream>>>((float4*)agg, hN / 4);
    k_msg6<<<nE / 128, 512, 0, stream>>>(e16, h16, src_s, dst_s, agg, nE);
    k_conv_mfma<<<(nN + 127) / 128, 256, 0, stream>>>(
        h16, agg, wT + (size_t)(1 + l) * 16384, cb1 + (size_t)l * HID,
        wT + (size_t)(4 + l) * 16384, cb2 + (size_t)l * HID, h16, nN);
  }

  k_zero4<<<(int)(((gN + nG) / 4 + 255) / 256), 256, 0, stream>>>((float4*)g, (gN + nG) / 4);
  k_counts<<<(nN + 255) / 256, 256, 0, stream>>>(batch, cnts, nN);
  k_pool2<<<(nN + 127) / 128, 256, 0, stream>>>(h16, batch, g, nN);
  k_head<<<nG, 128, 0, stream>>>(g, cnts, clw1, clb1, clw2, clb2,
                                 rw1, rb1, rw2, rb2, out, nG);
}